// Round 3
// baseline (129.033 us; speedup 1.0000x reference)
//
#include <hip/hip_runtime.h>
#include <math.h>

#define NQK 16   // Q*K = 4*4

// Single self-sufficient kernel: block = i (256 blocks x 512 threads).
// Each block rebuilds the j-side sin/cos tables in LDS (redundant across
// blocks but cheap: X0 is 512KB -> L2-resident), folds A/Bp and the i-side
// phase into rank-32 per-o weights, then does the 32-FMA/output contraction.
//
// V[i,j,o] = sum_qk  P[o,qk]*SJ[j,qk] + Qc[o,qk]*CJ[j,qk]
//   SJ/CJ = sin/cos(C[j,q]*k),  C = X0 @ Wc_w^T + Wc_b
//   P  = A*cos(Bp)*cos(w t k) - A*sin(Bp)*sin(w t k)
//   Qc = A*cos(Bp)*sin(w t k) + A*sin(Bp)*cos(w t k)
__global__ __launch_bounds__(512) void fused_kernel(
    const float* __restrict__ X0, const float* __restrict__ t,
    const float* __restrict__ Wc_w, const float* __restrict__ Wc_b,
    const float* __restrict__ w, const float* __restrict__ A,
    const float* __restrict__ Bp, float* __restrict__ out)
{
    __shared__ float SJ[256 * NQK];   // 16 KiB
    __shared__ float CJ[256 * NQK];   // 16 KiB

    const int i   = blockIdx.x;
    const int tid = threadIdx.x;
    const int o   = tid & 63;
    const int wv  = tid >> 6;         // wave id 0..7

    // ---- phase A: j-side tables. thread -> row j = tid>>1, q-pair (q0,q0+1)
    {
        const int j  = tid >> 1;           // 0..255
        const int q0 = (tid & 1) * 2;      // 0 or 2
        const float4* xr  = (const float4*)(X0 + (size_t)j * 512);
        const float4* wr0 = (const float4*)(Wc_w + (size_t)q0 * 512);
        const float4* wr1 = (const float4*)(Wc_w + (size_t)(q0 + 1) * 512);
        float acc0 = 0.f, acc1 = 0.f;
#pragma unroll 4
        for (int m = 0; m < 128; ++m) {
            float4 a = xr[m], b0 = wr0[m], b1 = wr1[m];
            acc0 += a.x * b0.x + a.y * b0.y + a.z * b0.z + a.w * b0.w;
            acc1 += a.x * b1.x + a.y * b1.y + a.z * b1.z + a.w * b1.w;
        }
        const float c0 = acc0 + Wc_b[q0];
        const float c1 = acc1 + Wc_b[q0 + 1];
#pragma unroll
        for (int k = 1; k <= 4; ++k) {
            float s, c;
            sincosf(c0 * (float)k, &s, &c);
            SJ[j * NQK + q0 * 4 + (k - 1)] = s;
            CJ[j * NQK + q0 * 4 + (k - 1)] = c;
            sincosf(c1 * (float)k, &s, &c);
            SJ[j * NQK + (q0 + 1) * 4 + (k - 1)] = s;
            CJ[j * NQK + (q0 + 1) * 4 + (k - 1)] = c;
        }
    }

    // ---- phase B: per-o rank-32 weights with i-phase folded in ----
    float P[NQK], Qc[NQK];
    {
        const float ti = t[i];
#pragma unroll
        for (int q = 0; q < 4; ++q) {
            const float wt = w[q] * ti;
#pragma unroll
            for (int k = 1; k <= 4; ++k) {
                const int qk = q * 4 + (k - 1);
                float si, ci, sb, cb;
                sincosf(wt * (float)k, &si, &ci);
                float a = A[o * NQK + qk];
                sincosf(Bp[o * NQK + qk], &sb, &cb);
                const float ap = a * cb, bq = a * sb;
                P[qk]  = ap * ci - bq * si;
                Qc[qk] = ap * si + bq * ci;
            }
        }
    }

    __syncthreads();

    // ---- phase C: contraction. wave wv: j in [wv*32, wv*32+32), lane = o.
    float* outb = out + (((size_t)i * 256) + (size_t)wv * 32) * 64 + o;
#pragma unroll 2
    for (int jj = 0; jj < 32; ++jj) {
        const int j = wv * 32 + jj;
        const float4* sj4 = (const float4*)(SJ + j * NQK);
        const float4* cj4 = (const float4*)(CJ + j * NQK);
        float acc = 0.f;
#pragma unroll
        for (int m = 0; m < 4; ++m) {
            float4 vs = sj4[m], vc = cj4[m];
            acc += P[4 * m + 0] * vs.x + Qc[4 * m + 0] * vc.x;
            acc += P[4 * m + 1] * vs.y + Qc[4 * m + 1] * vc.y;
            acc += P[4 * m + 2] * vs.z + Qc[4 * m + 2] * vc.z;
            acc += P[4 * m + 3] * vs.w + Qc[4 * m + 3] * vc.w;
        }
        outb[jj * 64] = acc;
    }
}

extern "C" void kernel_launch(void* const* d_in, const int* in_sizes, int n_in,
                              void* d_out, int out_size, void* d_ws, size_t ws_size,
                              hipStream_t stream) {
    const float* X0   = (const float*)d_in[0];
    const float* t    = (const float*)d_in[1];
    const float* Wc_w = (const float*)d_in[2];
    const float* Wc_b = (const float*)d_in[3];
    const float* w    = (const float*)d_in[4];
    const float* A    = (const float*)d_in[5];
    const float* Bp   = (const float*)d_in[6];
    float* out = (float*)d_out;

    fused_kernel<<<dim3(256), dim3(512), 0, stream>>>(
        X0, t, Wc_w, Wc_b, w, A, Bp, out);
}